// Round 19
// baseline (603.896 us; speedup 1.0000x reference)
//
#include <hip/hip_runtime.h>

// GRU: B=256, T=1000, I=64, H=128 (3H=384).
// Round-19 = r12 (594us best) + ONE isolated change: packed b32 h-writes.
// Ledger: MFMA-count (r16, negative), VALU-count (r13, neutral), resched
// (r15, negative), store-drain (r17, neutral), vmcnt-drain (r18, neutral).
// Remaining measured component: 6.1M LDS bank conflicts ~192 cyc/step/CU.
// ds_read_b128 pattern is already minimal-2x (free, m136); suspect is the
// b16 h-writes where lane pairs hit the same dword (68*mA + j/2). Fix:
// DPP lane^1 pack -> even lanes issue one aligned ds_write_b32 per row.

#define Tc 1000
#define Ic 64
#define Hc 128
#define Bc 256
#define MBLK 8
#define NBLOCKS 32

typedef _Float16 half8 __attribute__((ext_vector_type(8)));
typedef float f32x4 __attribute__((ext_vector_type(4)));

#define MFMA_F16(A, B, C) __builtin_amdgcn_mfma_f32_16x16x32_f16((A), (B), (C), 0, 0, 0)

__device__ __forceinline__ float fast_sigmoid(float x) {
    return __builtin_amdgcn_rcpf(1.0f + __expf(-x));
}
__device__ __forceinline__ float fast_tanh(float x) {
    return 1.0f - 2.0f * __builtin_amdgcn_rcpf(__expf(2.0f * x) + 1.0f);
}
// value from lane^1 within the quad (all lanes active at call site)
__device__ __forceinline__ unsigned dpp_xor1(unsigned x) {
    return (unsigned)__builtin_amdgcn_update_dpp(0, (int)x, 0xB1, 0xF, 0xF, true);
}

__global__ __launch_bounds__(512, 2) void gru_mfma_kernel(
    const float* __restrict__ input,   // [B][T][I]
    const float* __restrict__ W_ih,    // [3H][I]
    const float* __restrict__ W_hh,    // [3H][H]
    const float* __restrict__ b_ih,    // [3H]
    const float* __restrict__ b_hh,    // [3H]
    float* __restrict__ out)           // states [B][T][H] then hT [B][H]
{
    const int blk = blockIdx.x;
    const int tid = threadIdx.x;
    const int l   = tid & 63;
    const int w   = tid >> 6;    // wave 0..7
    const int ln  = l & 15;      // A-row m / B-col n offset
    const int lg  = l >> 4;      // k-group 0..3
    const int j   = w * 16 + ln; // this lane's gate column / h-unit
    const bool hi = (l >= 32);

    __shared__ __align__(16) _Float16 hbuf[2][16][136];  // h(t) f16; rows 8-15 stay 0
    __shared__ __align__(16) _Float16 xbuf[2][16][72];   // x rows f16; rows 8-15 stay 0

    // ---------- persistent B-fragments (identical to r11/r12, verified) ----------
    half8 bh[3][4], bx[3][2];
#pragma unroll
    for (int g = 0; g < 3; ++g) {
        const float* rw = W_hh + (size_t)(g * Hc + j) * Hc;
#pragma unroll
        for (int kc = 0; kc < 4; ++kc) {
            const float* p = rw + kc * 32 + lg * 8;
            half8 f;
#pragma unroll
            for (int e = 0; e < 8; ++e) f[e] = (_Float16)p[e];
            bh[g][kc] = f;
        }
        const float* rx = W_ih + (size_t)(g * Hc + j) * Ic;
#pragma unroll
        for (int kc = 0; kc < 2; ++kc) {
            const float* p = rx + kc * 32 + lg * 8;
            half8 f;
#pragma unroll
            for (int e = 0; e < 8; ++e) f[e] = (_Float16)p[e];
            bx[g][kc] = f;
        }
    }

    const float br0 = b_ih[j] + b_hh[j];
    const float bz0 = b_ih[Hc + j] + b_hh[Hc + j];
    const float bnx = b_ih[2 * Hc + j];
    const float bnh = b_hh[2 * Hc + j];

    // ---------- input staging geometry (8 real rows) ----------
    const int  sm  = tid >> 5;          // 0..15
    const int  sk  = (tid & 31) * 2;
    const bool stg = sm < MBLK;
    const float* inrow = input + (size_t)(blk * MBLK + (stg ? sm : 0)) * Tc * Ic + sk;

    // zero all of hbuf/xbuf (h(-1)=0; pad rows stay 0 forever)
    for (int i = tid; i < 2 * 16 * 136; i += 512) (&hbuf[0][0][0])[i] = (_Float16)0.0f;
    for (int i = tid; i < 2 * 16 * 72;  i += 512) (&xbuf[0][0][0])[i] = (_Float16)0.0f;
    __syncthreads();

    float2 xpre0 = {0.f, 0.f}, xpre1 = {0.f, 0.f};
    if (stg) {   // stage x rows 0,1; prefetch rows 2,3
        float2 v0 = *reinterpret_cast<const float2*>(inrow);
        float2 v1 = *reinterpret_cast<const float2*>(inrow + Ic);
        union { _Float16 h[2]; unsigned u; } p0, p1;
        p0.h[0] = (_Float16)v0.x; p0.h[1] = (_Float16)v0.y;
        p1.h[0] = (_Float16)v1.x; p1.h[1] = (_Float16)v1.y;
        *reinterpret_cast<unsigned*>(&xbuf[0][sm][sk]) = p0.u;
        *reinterpret_cast<unsigned*>(&xbuf[1][sm][sk]) = p1.u;
        xpre0 = *reinterpret_cast<const float2*>(inrow + 2 * Ic);
        xpre1 = *reinterpret_cast<const float2*>(inrow + 3 * Ic);
    }
    __syncthreads();

    // ---------- prologue: x-projection for t=0 ----------
    f32x4 cr  = {br0, br0, br0, br0};
    f32x4 cz  = {bz0, bz0, bz0, bz0};
    f32x4 cxn = {bnx, bnx, bnx, bnx};
    {
        const _Float16* xr = &xbuf[0][ln][lg * 8];
        half8 xa0 = *reinterpret_cast<const half8*>(xr);
        half8 xa1 = *reinterpret_cast<const half8*>(xr + 32);
        cr  = MFMA_F16(xa0, bx[0][0], cr);  cr  = MFMA_F16(xa1, bx[0][1], cr);
        cz  = MFMA_F16(xa0, bx[1][0], cz);  cz  = MFMA_F16(xa1, bx[1][1], cz);
        cxn = MFMA_F16(xa0, bx[2][0], cxn); cxn = MFMA_F16(xa1, bx[2][1], cxn);
    }
    float holdA = 0.f, holdB = 0.f;

    // this lane's two owned batch rows after redistribution
    const int mA = (lg & 1) * 4 + (hi ? 2 : 0);
    const int mB = mA + 1;
    float* sA  = out + (size_t)(blk * MBLK + mA) * Tc * Hc + j;   // states run-ptr
    float* sB  = out + (size_t)(blk * MBLK + mB) * Tc * Hc + j;
    float* hTp = out + (size_t)Bc * Tc * Hc;

#define GRU_STEP(T_, PAR_, XPRE_)                                               \
    {                                                                           \
        __syncthreads();                                                        \
        const _Float16* hrp = &hbuf[1 - (PAR_)][ln][lg * 8];                    \
        half8 ha0 = *reinterpret_cast<const half8*>(hrp);                       \
        half8 ha1 = *reinterpret_cast<const half8*>(hrp + 32);                  \
        half8 ha2 = *reinterpret_cast<const half8*>(hrp + 64);                  \
        half8 ha3 = *reinterpret_cast<const half8*>(hrp + 96);                  \
        f32x4 chn = {bnh, bnh, bnh, bnh};                                       \
        cr = MFMA_F16(ha0, bh[0][0], cr); cz = MFMA_F16(ha0, bh[1][0], cz);     \
        chn = MFMA_F16(ha0, bh[2][0], chn);                                     \
        cr = MFMA_F16(ha1, bh[0][1], cr); cz = MFMA_F16(ha1, bh[1][1], cz);     \
        chn = MFMA_F16(ha1, bh[2][1], chn);                                     \
        cr = MFMA_F16(ha2, bh[0][2], cr); cz = MFMA_F16(ha2, bh[1][2], cz);     \
        chn = MFMA_F16(ha2, bh[2][2], chn);                                     \
        cr = MFMA_F16(ha3, bh[0][3], cr); cz = MFMA_F16(ha3, bh[1][3], cz);     \
        chn = MFMA_F16(ha3, bh[2][3], chn);                                     \
        const _Float16* xrp = &xbuf[1 - (PAR_)][ln][lg * 8];                    \
        half8 xa0 = *reinterpret_cast<const half8*>(xrp);                       \
        half8 xa1 = *reinterpret_cast<const half8*>(xrp + 32);                  \
        f32x4 nr = {br0, br0, br0, br0};                                        \
        f32x4 nz = {bz0, bz0, bz0, bz0};                                        \
        f32x4 nx = {bnx, bnx, bnx, bnx};                                        \
        nr = MFMA_F16(xa0, bx[0][0], nr); nr = MFMA_F16(xa1, bx[0][1], nr);     \
        nz = MFMA_F16(xa0, bx[1][0], nz); nz = MFMA_F16(xa1, bx[1][1], nz);     \
        nx = MFMA_F16(xa0, bx[2][0], nx); nx = MFMA_F16(xa1, bx[2][1], nx);     \
        if (stg) {                                                              \
            union { _Float16 h[2]; unsigned u; } pk;                            \
            pk.h[0] = (_Float16)XPRE_.x; pk.h[1] = (_Float16)XPRE_.y;           \
            *reinterpret_cast<unsigned*>(&xbuf[PAR_][sm][sk]) = pk.u;           \
            const int trow = ((T_) + 4 < Tc) ? ((T_) + 4) : (Tc - 1);           \
            XPRE_ = *reinterpret_cast<const float2*>(inrow + (size_t)trow * Ic);\
        }                                                                       \
        /* redistribute elems 2,3 to the upper half-wave */                     \
        const float tR2 = __shfl_xor(cr[2], 32),  tR3 = __shfl_xor(cr[3], 32);  \
        const float tZ2 = __shfl_xor(cz[2], 32),  tZ3 = __shfl_xor(cz[3], 32);  \
        const float tX2 = __shfl_xor(cxn[2], 32), tX3 = __shfl_xor(cxn[3], 32); \
        const float tH2 = __shfl_xor(chn[2], 32), tH3 = __shfl_xor(chn[3], 32); \
        const float aR = hi ? tR2 : cr[0],  bR = hi ? tR3 : cr[1];              \
        const float aZ = hi ? tZ2 : cz[0],  bZ = hi ? tZ3 : cz[1];              \
        const float aX = hi ? tX2 : cxn[0], bX = hi ? tX3 : cxn[1];             \
        const float aH = hi ? tH2 : chn[0], bH = hi ? tH3 : chn[1];             \
        const float rgA = fast_sigmoid(aR), zgA = fast_sigmoid(aZ);             \
        const float nvA = fast_tanh(aX + rgA * aH);                             \
        const float hA  = nvA + zgA * (holdA - nvA);                            \
        const float rgB = fast_sigmoid(bR), zgB = fast_sigmoid(bZ);             \
        const float nvB = fast_tanh(bX + rgB * bH);                             \
        const float hB  = nvB + zgB * (holdB - nvB);                            \
        /* packed b32 h-writes: even lanes write (own | lane^1 <<16) */         \
        {                                                                       \
            const unsigned uA = (unsigned)__builtin_bit_cast(unsigned short, (_Float16)hA); \
            const unsigned uB = (unsigned)__builtin_bit_cast(unsigned short, (_Float16)hB); \
            const unsigned nA = dpp_xor1(uA);                                   \
            const unsigned nB = dpp_xor1(uB);                                   \
            if (!(ln & 1)) {                                                    \
                *reinterpret_cast<unsigned*>(&hbuf[PAR_][mA][j]) = uA | (nA << 16); \
                *reinterpret_cast<unsigned*>(&hbuf[PAR_][mB][j]) = uB | (nB << 16); \
            }                                                                   \
        }                                                                       \
        *sA = hA; sA += Hc;                                                     \
        *sB = hB; sB += Hc;                                                     \
        if ((T_) == Tc - 1) {                                                   \
            hTp[(size_t)(blk * MBLK + mA) * Hc + j] = hA;                       \
            hTp[(size_t)(blk * MBLK + mB) * Hc + j] = hB;                       \
        }                                                                       \
        cr = nr; cz = nz; cxn = nx; holdA = hA; holdB = hB;                     \
    }

    for (int t = 0; t < Tc; t += 2) {
        GRU_STEP(t, 0, xpre0);
        GRU_STEP(t + 1, 1, xpre1);
    }
#undef GRU_STEP
}

extern "C" void kernel_launch(void* const* d_in, const int* in_sizes, int n_in,
                              void* d_out, int out_size, void* d_ws, size_t ws_size,
                              hipStream_t stream) {
    const float* input = (const float*)d_in[0];
    const float* W_ih  = (const float*)d_in[1];
    const float* W_hh  = (const float*)d_in[2];
    const float* b_ih  = (const float*)d_in[3];
    const float* b_hh  = (const float*)d_in[4];
    float* out = (float*)d_out;
    (void)in_sizes; (void)n_in; (void)d_ws; (void)ws_size; (void)out_size;

    gru_mfma_kernel<<<NBLOCKS, 512, 0, stream>>>(input, W_ih, W_hh, b_ih, b_hh, out);
}

// Round 20
// 476.540 us; speedup vs baseline: 1.2673x; 1.2673x over previous
//
#include <hip/hip_runtime.h>

// GRU: B=256, T=1000, I=64, H=128 (3H=384).
// Round-20 = r12 + ONE structural simplification: interleaved real rows.
// Evidence r19: conflicts byte-identical (6146048) with packed h-writes ->
// writes exonerated; the 8 __shfl_xor(.,32) (= ds_bpermute, LDS pipe,
// ~40cyc each, SERIAL between MFMA results and gates) are the remaining
// LDS+latency suspect. Fix: real batch rows at tile rows {0,1,4,5,8,9,12,13}
// (TROW(b')=4*(b'>>1)+(b'&1)) so every lane's C elems 0,1 are real ->
// each lane owns batch rows 2*lg, 2*lg+1 directly. ZERO cross-lane ops.
// Staging/store row-map adjusted; everything else byte-identical to r12.

#define Tc 1000
#define Ic 64
#define Hc 128
#define Bc 256
#define MBLK 8
#define NBLOCKS 32

// batch row (0..7) -> tile row in {0,1,4,5,8,9,12,13}
#define TROW(b_) ((((b_) >> 1) << 2) | ((b_) & 1))

typedef _Float16 half8 __attribute__((ext_vector_type(8)));
typedef float f32x4 __attribute__((ext_vector_type(4)));

#define MFMA_F16(A, B, C) __builtin_amdgcn_mfma_f32_16x16x32_f16((A), (B), (C), 0, 0, 0)

__device__ __forceinline__ float fast_sigmoid(float x) {
    return __builtin_amdgcn_rcpf(1.0f + __expf(-x));
}
__device__ __forceinline__ float fast_tanh(float x) {
    return 1.0f - 2.0f * __builtin_amdgcn_rcpf(__expf(2.0f * x) + 1.0f);
}

__global__ __launch_bounds__(512, 2) void gru_mfma_kernel(
    const float* __restrict__ input,   // [B][T][I]
    const float* __restrict__ W_ih,    // [3H][I]
    const float* __restrict__ W_hh,    // [3H][H]
    const float* __restrict__ b_ih,    // [3H]
    const float* __restrict__ b_hh,    // [3H]
    float* __restrict__ out)           // states [B][T][H] then hT [B][H]
{
    const int blk = blockIdx.x;
    const int tid = threadIdx.x;
    const int l   = tid & 63;
    const int w   = tid >> 6;    // wave 0..7
    const int ln  = l & 15;      // A-row m / B-col n offset
    const int lg  = l >> 4;      // k-group 0..3
    const int j   = w * 16 + ln; // this lane's gate column / h-unit

    __shared__ __align__(16) _Float16 hbuf[2][16][136];  // pad tile-rows stay 0
    __shared__ __align__(16) _Float16 xbuf[2][16][72];   // pad tile-rows stay 0

    // ---------- persistent B-fragments (identical to r11/r12, verified) ----------
    half8 bh[3][4], bx[3][2];
#pragma unroll
    for (int g = 0; g < 3; ++g) {
        const float* rw = W_hh + (size_t)(g * Hc + j) * Hc;
#pragma unroll
        for (int kc = 0; kc < 4; ++kc) {
            const float* p = rw + kc * 32 + lg * 8;
            half8 f;
#pragma unroll
            for (int e = 0; e < 8; ++e) f[e] = (_Float16)p[e];
            bh[g][kc] = f;
        }
        const float* rx = W_ih + (size_t)(g * Hc + j) * Ic;
#pragma unroll
        for (int kc = 0; kc < 2; ++kc) {
            const float* p = rx + kc * 32 + lg * 8;
            half8 f;
#pragma unroll
            for (int e = 0; e < 8; ++e) f[e] = (_Float16)p[e];
            bx[g][kc] = f;
        }
    }

    const float br0 = b_ih[j] + b_hh[j];
    const float bz0 = b_ih[Hc + j] + b_hh[Hc + j];
    const float bnx = b_ih[2 * Hc + j];
    const float bnh = b_hh[2 * Hc + j];

    // ---------- input staging geometry (8 real rows, interleaved tile rows) ----
    const int  sm  = tid >> 5;          // 0..15 (batch row within block)
    const int  sk  = (tid & 31) * 2;
    const bool stg = sm < MBLK;
    const int  srow = TROW(sm & 7);     // tile row for this stager
    const float* inrow = input + (size_t)(blk * MBLK + (stg ? sm : 0)) * Tc * Ic + sk;

    // zero all of hbuf/xbuf (h(-1)=0; pad tile-rows stay 0 forever)
    for (int i = tid; i < 2 * 16 * 136; i += 512) (&hbuf[0][0][0])[i] = (_Float16)0.0f;
    for (int i = tid; i < 2 * 16 * 72;  i += 512) (&xbuf[0][0][0])[i] = (_Float16)0.0f;
    __syncthreads();

    float2 xpre0 = {0.f, 0.f}, xpre1 = {0.f, 0.f};
    if (stg) {   // stage x rows 0,1; prefetch rows 2,3
        float2 v0 = *reinterpret_cast<const float2*>(inrow);
        float2 v1 = *reinterpret_cast<const float2*>(inrow + Ic);
        union { _Float16 h[2]; unsigned u; } p0, p1;
        p0.h[0] = (_Float16)v0.x; p0.h[1] = (_Float16)v0.y;
        p1.h[0] = (_Float16)v1.x; p1.h[1] = (_Float16)v1.y;
        *reinterpret_cast<unsigned*>(&xbuf[0][srow][sk]) = p0.u;
        *reinterpret_cast<unsigned*>(&xbuf[1][srow][sk]) = p1.u;
        xpre0 = *reinterpret_cast<const float2*>(inrow + 2 * Ic);
        xpre1 = *reinterpret_cast<const float2*>(inrow + 3 * Ic);
    }
    __syncthreads();

    // ---------- prologue: x-projection for t=0 ----------
    f32x4 cr  = {br0, br0, br0, br0};
    f32x4 cz  = {bz0, bz0, bz0, bz0};
    f32x4 cxn = {bnx, bnx, bnx, bnx};
    {
        const _Float16* xr = &xbuf[0][ln][lg * 8];
        half8 xa0 = *reinterpret_cast<const half8*>(xr);
        half8 xa1 = *reinterpret_cast<const half8*>(xr + 32);
        cr  = MFMA_F16(xa0, bx[0][0], cr);  cr  = MFMA_F16(xa1, bx[0][1], cr);
        cz  = MFMA_F16(xa0, bx[1][0], cz);  cz  = MFMA_F16(xa1, bx[1][1], cz);
        cxn = MFMA_F16(xa0, bx[2][0], cxn); cxn = MFMA_F16(xa1, bx[2][1], cxn);
    }
    float holdA = 0.f, holdB = 0.f;

    // this lane directly owns batch rows 2lg, 2lg+1 (C elems 0,1 = tile rows 4lg, 4lg+1)
    const int bA = blk * MBLK + 2 * lg;
    const int bB = bA + 1;
    const int tA = 4 * lg;       // tile row of elem 0
    const int tB = tA + 1;       // tile row of elem 1
    float* sA  = out + (size_t)bA * Tc * Hc + j;   // states run-ptr
    float* sB  = out + (size_t)bB * Tc * Hc + j;
    float* hTp = out + (size_t)Bc * Tc * Hc;

#define GRU_STEP(T_, PAR_, XPRE_)                                               \
    {                                                                           \
        __syncthreads();                                                        \
        const _Float16* hrp = &hbuf[1 - (PAR_)][ln][lg * 8];                    \
        half8 ha0 = *reinterpret_cast<const half8*>(hrp);                       \
        half8 ha1 = *reinterpret_cast<const half8*>(hrp + 32);                  \
        half8 ha2 = *reinterpret_cast<const half8*>(hrp + 64);                  \
        half8 ha3 = *reinterpret_cast<const half8*>(hrp + 96);                  \
        f32x4 chn = {bnh, bnh, bnh, bnh};                                       \
        cr = MFMA_F16(ha0, bh[0][0], cr); cz = MFMA_F16(ha0, bh[1][0], cz);     \
        chn = MFMA_F16(ha0, bh[2][0], chn);                                     \
        cr = MFMA_F16(ha1, bh[0][1], cr); cz = MFMA_F16(ha1, bh[1][1], cz);     \
        chn = MFMA_F16(ha1, bh[2][1], chn);                                     \
        cr = MFMA_F16(ha2, bh[0][2], cr); cz = MFMA_F16(ha2, bh[1][2], cz);     \
        chn = MFMA_F16(ha2, bh[2][2], chn);                                     \
        cr = MFMA_F16(ha3, bh[0][3], cr); cz = MFMA_F16(ha3, bh[1][3], cz);     \
        chn = MFMA_F16(ha3, bh[2][3], chn);                                     \
        const _Float16* xrp = &xbuf[1 - (PAR_)][ln][lg * 8];                    \
        half8 xa0 = *reinterpret_cast<const half8*>(xrp);                       \
        half8 xa1 = *reinterpret_cast<const half8*>(xrp + 32);                  \
        f32x4 nr = {br0, br0, br0, br0};                                        \
        f32x4 nz = {bz0, bz0, bz0, bz0};                                        \
        f32x4 nx = {bnx, bnx, bnx, bnx};                                        \
        nr = MFMA_F16(xa0, bx[0][0], nr); nr = MFMA_F16(xa1, bx[0][1], nr);     \
        nz = MFMA_F16(xa0, bx[1][0], nz); nz = MFMA_F16(xa1, bx[1][1], nz);     \
        nx = MFMA_F16(xa0, bx[2][0], nx); nx = MFMA_F16(xa1, bx[2][1], nx);     \
        if (stg) {                                                              \
            union { _Float16 h[2]; unsigned u; } pk;                            \
            pk.h[0] = (_Float16)XPRE_.x; pk.h[1] = (_Float16)XPRE_.y;           \
            *reinterpret_cast<unsigned*>(&xbuf[PAR_][srow][sk]) = pk.u;         \
            const int trow = ((T_) + 4 < Tc) ? ((T_) + 4) : (Tc - 1);           \
            XPRE_ = *reinterpret_cast<const float2*>(inrow + (size_t)trow * Ic);\
        }                                                                       \
        /* no redistribution: elems 0,1 ARE this lane's rows */                 \
        const float rgA = fast_sigmoid(cr[0]), zgA = fast_sigmoid(cz[0]);       \
        const float nvA = fast_tanh(cxn[0] + rgA * chn[0]);                     \
        const float hA  = nvA + zgA * (holdA - nvA);                            \
        const float rgB = fast_sigmoid(cr[1]), zgB = fast_sigmoid(cz[1]);       \
        const float nvB = fast_tanh(cxn[1] + rgB * chn[1]);                     \
        const float hB  = nvB + zgB * (holdB - nvB);                            \
        hbuf[PAR_][tA][j] = (_Float16)hA;                                       \
        hbuf[PAR_][tB][j] = (_Float16)hB;                                       \
        *sA = hA; sA += Hc;                                                     \
        *sB = hB; sB += Hc;                                                     \
        if ((T_) == Tc - 1) {                                                   \
            hTp[(size_t)bA * Hc + j] = hA;                                      \
            hTp[(size_t)bB * Hc + j] = hB;                                      \
        }                                                                       \
        cr = nr; cz = nz; cxn = nx; holdA = hA; holdB = hB;                     \
    }

    for (int t = 0; t < Tc; t += 2) {
        GRU_STEP(t, 0, xpre0);
        GRU_STEP(t + 1, 1, xpre1);
    }
#undef GRU_STEP
}

extern "C" void kernel_launch(void* const* d_in, const int* in_sizes, int n_in,
                              void* d_out, int out_size, void* d_ws, size_t ws_size,
                              hipStream_t stream) {
    const float* input = (const float*)d_in[0];
    const float* W_ih  = (const float*)d_in[1];
    const float* W_hh  = (const float*)d_in[2];
    const float* b_ih  = (const float*)d_in[3];
    const float* b_hh  = (const float*)d_in[4];
    float* out = (float*)d_out;
    (void)in_sizes; (void)n_in; (void)d_ws; (void)ws_size; (void)out_size;

    gru_mfma_kernel<<<NBLOCKS, 512, 0, stream>>>(input, W_ih, W_hh, b_ih, b_hh, out);
}

// Round 21
// 414.336 us; speedup vs baseline: 1.4575x; 1.1501x over previous
//
#include <hip/hip_runtime.h>

// GRU: B=256, T=1000, I=64, H=128 (3H=384).
// Round-21 = r20's zero-shuffle interleave applied to M=4 x 64 blocks.
// r20 (594->483us) proved the 8 ds_bpermutes were ~270cyc/step of serial
// cost; r13's M=4 attempt (616us) carried 12 of them + select chains.
// Now: real rows at tile rows {0,4,8,12} (=4*lg) -> each lane's C elem 0
// is its own batch row. ONE gate-triple/lane (6 TRANS), one h-write, one
// states store, zero cross-lane ops. On-CU VALU ~45%->~25%; MFMA per CU
// unchanged but over 2x CUs. Everything else byte-identical to r20.

#define Tc 1000
#define Ic 64
#define Hc 128
#define Bc 256
#define MBLK 4
#define NBLOCKS 64

typedef _Float16 half8 __attribute__((ext_vector_type(8)));
typedef float f32x4 __attribute__((ext_vector_type(4)));

#define MFMA_F16(A, B, C) __builtin_amdgcn_mfma_f32_16x16x32_f16((A), (B), (C), 0, 0, 0)

__device__ __forceinline__ float fast_sigmoid(float x) {
    return __builtin_amdgcn_rcpf(1.0f + __expf(-x));
}
__device__ __forceinline__ float fast_tanh(float x) {
    return 1.0f - 2.0f * __builtin_amdgcn_rcpf(__expf(2.0f * x) + 1.0f);
}

__global__ __launch_bounds__(512, 2) void gru_mfma_kernel(
    const float* __restrict__ input,   // [B][T][I]
    const float* __restrict__ W_ih,    // [3H][I]
    const float* __restrict__ W_hh,    // [3H][H]
    const float* __restrict__ b_ih,    // [3H]
    const float* __restrict__ b_hh,    // [3H]
    float* __restrict__ out)           // states [B][T][H] then hT [B][H]
{
    const int blk = blockIdx.x;
    const int tid = threadIdx.x;
    const int l   = tid & 63;
    const int w   = tid >> 6;    // wave 0..7
    const int ln  = l & 15;      // A-row m / B-col n offset
    const int lg  = l >> 4;      // k-group 0..3
    const int j   = w * 16 + ln; // this lane's gate column / h-unit

    __shared__ __align__(16) _Float16 hbuf[2][16][136];  // pad tile-rows stay 0
    __shared__ __align__(16) _Float16 xbuf[2][16][72];   // pad tile-rows stay 0

    // ---------- persistent B-fragments (identical to r11/r12/r20, verified) ----
    half8 bh[3][4], bx[3][2];
#pragma unroll
    for (int g = 0; g < 3; ++g) {
        const float* rw = W_hh + (size_t)(g * Hc + j) * Hc;
#pragma unroll
        for (int kc = 0; kc < 4; ++kc) {
            const float* p = rw + kc * 32 + lg * 8;
            half8 f;
#pragma unroll
            for (int e = 0; e < 8; ++e) f[e] = (_Float16)p[e];
            bh[g][kc] = f;
        }
        const float* rx = W_ih + (size_t)(g * Hc + j) * Ic;
#pragma unroll
        for (int kc = 0; kc < 2; ++kc) {
            const float* p = rx + kc * 32 + lg * 8;
            half8 f;
#pragma unroll
            for (int e = 0; e < 8; ++e) f[e] = (_Float16)p[e];
            bx[g][kc] = f;
        }
    }

    const float br0 = b_ih[j] + b_hh[j];
    const float bz0 = b_ih[Hc + j] + b_hh[Hc + j];
    const float bnx = b_ih[2 * Hc + j];
    const float bnh = b_hh[2 * Hc + j];

    // ---------- input staging geometry (4 real rows at tile rows 4*b') ----------
    const int  sm  = tid >> 5;          // 0..15 (batch row within block)
    const int  sk  = (tid & 31) * 2;
    const bool stg = sm < MBLK;
    const int  srow = 4 * sm;           // tile row for this stager (sm<4)
    const float* inrow = input + (size_t)(blk * MBLK + (stg ? sm : 0)) * Tc * Ic + sk;

    // zero all of hbuf/xbuf (h(-1)=0; pad tile-rows stay 0 forever)
    for (int i = tid; i < 2 * 16 * 136; i += 512) (&hbuf[0][0][0])[i] = (_Float16)0.0f;
    for (int i = tid; i < 2 * 16 * 72;  i += 512) (&xbuf[0][0][0])[i] = (_Float16)0.0f;
    __syncthreads();

    float2 xpre0 = {0.f, 0.f}, xpre1 = {0.f, 0.f};
    if (stg) {   // stage x rows 0,1; prefetch rows 2,3
        float2 v0 = *reinterpret_cast<const float2*>(inrow);
        float2 v1 = *reinterpret_cast<const float2*>(inrow + Ic);
        union { _Float16 h[2]; unsigned u; } p0, p1;
        p0.h[0] = (_Float16)v0.x; p0.h[1] = (_Float16)v0.y;
        p1.h[0] = (_Float16)v1.x; p1.h[1] = (_Float16)v1.y;
        *reinterpret_cast<unsigned*>(&xbuf[0][srow][sk]) = p0.u;
        *reinterpret_cast<unsigned*>(&xbuf[1][srow][sk]) = p1.u;
        xpre0 = *reinterpret_cast<const float2*>(inrow + 2 * Ic);
        xpre1 = *reinterpret_cast<const float2*>(inrow + 3 * Ic);
    }
    __syncthreads();

    // ---------- prologue: x-projection for t=0 ----------
    f32x4 cr  = {br0, br0, br0, br0};
    f32x4 cz  = {bz0, bz0, bz0, bz0};
    f32x4 cxn = {bnx, bnx, bnx, bnx};
    {
        const _Float16* xr = &xbuf[0][ln][lg * 8];
        half8 xa0 = *reinterpret_cast<const half8*>(xr);
        half8 xa1 = *reinterpret_cast<const half8*>(xr + 32);
        cr  = MFMA_F16(xa0, bx[0][0], cr);  cr  = MFMA_F16(xa1, bx[0][1], cr);
        cz  = MFMA_F16(xa0, bx[1][0], cz);  cz  = MFMA_F16(xa1, bx[1][1], cz);
        cxn = MFMA_F16(xa0, bx[2][0], cxn); cxn = MFMA_F16(xa1, bx[2][1], cxn);
    }
    float hold = 0.f;

    // this lane directly owns batch row blk*4+lg (C elem 0 = tile row 4*lg)
    const int bA = blk * MBLK + lg;
    const int tA = 4 * lg;       // tile row of elem 0
    float* sP  = out + (size_t)bA * Tc * Hc + j;   // states run-ptr
    float* hTp = out + (size_t)Bc * Tc * Hc + (size_t)bA * Hc + j;

#define GRU_STEP(T_, PAR_, XPRE_)                                               \
    {                                                                           \
        __syncthreads();                                                        \
        const _Float16* hrp = &hbuf[1 - (PAR_)][ln][lg * 8];                    \
        half8 ha0 = *reinterpret_cast<const half8*>(hrp);                       \
        half8 ha1 = *reinterpret_cast<const half8*>(hrp + 32);                  \
        half8 ha2 = *reinterpret_cast<const half8*>(hrp + 64);                  \
        half8 ha3 = *reinterpret_cast<const half8*>(hrp + 96);                  \
        f32x4 chn = {bnh, bnh, bnh, bnh};                                       \
        cr = MFMA_F16(ha0, bh[0][0], cr); cz = MFMA_F16(ha0, bh[1][0], cz);     \
        chn = MFMA_F16(ha0, bh[2][0], chn);                                     \
        cr = MFMA_F16(ha1, bh[0][1], cr); cz = MFMA_F16(ha1, bh[1][1], cz);     \
        chn = MFMA_F16(ha1, bh[2][1], chn);                                     \
        cr = MFMA_F16(ha2, bh[0][2], cr); cz = MFMA_F16(ha2, bh[1][2], cz);     \
        chn = MFMA_F16(ha2, bh[2][2], chn);                                     \
        cr = MFMA_F16(ha3, bh[0][3], cr); cz = MFMA_F16(ha3, bh[1][3], cz);     \
        chn = MFMA_F16(ha3, bh[2][3], chn);                                     \
        const _Float16* xrp = &xbuf[1 - (PAR_)][ln][lg * 8];                    \
        half8 xa0 = *reinterpret_cast<const half8*>(xrp);                       \
        half8 xa1 = *reinterpret_cast<const half8*>(xrp + 32);                  \
        f32x4 nr = {br0, br0, br0, br0};                                        \
        f32x4 nz = {bz0, bz0, bz0, bz0};                                        \
        f32x4 nx = {bnx, bnx, bnx, bnx};                                        \
        nr = MFMA_F16(xa0, bx[0][0], nr); nr = MFMA_F16(xa1, bx[0][1], nr);     \
        nz = MFMA_F16(xa0, bx[1][0], nz); nz = MFMA_F16(xa1, bx[1][1], nz);     \
        nx = MFMA_F16(xa0, bx[2][0], nx); nx = MFMA_F16(xa1, bx[2][1], nx);     \
        if (stg) {                                                              \
            union { _Float16 h[2]; unsigned u; } pk;                            \
            pk.h[0] = (_Float16)XPRE_.x; pk.h[1] = (_Float16)XPRE_.y;           \
            *reinterpret_cast<unsigned*>(&xbuf[PAR_][srow][sk]) = pk.u;         \
            const int trow = ((T_) + 4 < Tc) ? ((T_) + 4) : (Tc - 1);           \
            XPRE_ = *reinterpret_cast<const float2*>(inrow + (size_t)trow * Ic);\
        }                                                                       \
        /* no redistribution: elem 0 IS this lane's row */                      \
        const float rg = fast_sigmoid(cr[0]), zg = fast_sigmoid(cz[0]);         \
        const float nv = fast_tanh(cxn[0] + rg * chn[0]);                       \
        const float hN = nv + zg * (hold - nv);                                 \
        hbuf[PAR_][tA][j] = (_Float16)hN;                                       \
        *sP = hN; sP += Hc;                                                     \
        if ((T_) == Tc - 1) *hTp = hN;                                          \
        cr = nr; cz = nz; cxn = nx; hold = hN;                                  \
    }

    for (int t = 0; t < Tc; t += 2) {
        GRU_STEP(t, 0, xpre0);
        GRU_STEP(t + 1, 1, xpre1);
    }
#undef GRU_STEP
}

extern "C" void kernel_launch(void* const* d_in, const int* in_sizes, int n_in,
                              void* d_out, int out_size, void* d_ws, size_t ws_size,
                              hipStream_t stream) {
    const float* input = (const float*)d_in[0];
    const float* W_ih  = (const float*)d_in[1];
    const float* W_hh  = (const float*)d_in[2];
    const float* b_ih  = (const float*)d_in[3];
    const float* b_hh  = (const float*)d_in[4];
    float* out = (float*)d_out;
    (void)in_sizes; (void)n_in; (void)d_ws; (void)ws_size; (void)out_size;

    gru_mfma_kernel<<<NBLOCKS, 512, 0, stream>>>(input, W_ih, W_hh, b_ih, b_hh, out);
}

// Round 22
// 355.396 us; speedup vs baseline: 1.6992x; 1.1658x over previous
//
#include <hip/hip_runtime.h>

// GRU: B=256, T=1000, I=64, H=128 (3H=384).
// Round-22 = r21 (426us) + x-proj amortized over 4-step windows.
// r21 counters: on-CU MFMA 56% + VALU 35% = 91%; MFMA pipe = 36/SIMD/step
// x ~16cyc = 576cyc is the largest term and is M-split-invariant.
// x-proj is h-independent: pack x(t0..t0+3) of the 4 real batch rows into
// the 16 tile rows (row 4b'+i = batch b', offset i) -> ONE x-MFMA block
// (6 MFMAs) per 4 steps; lane's C elems 0..3 = its own row's x-proj for
// the window's 4 steps (compile-time indexed). MFMA/SIMD/step 36->27.
// Staging frequency drops 4x. h-recurrence/gates/stores = r21 verbatim.

#define Tc 1000
#define Ic 64
#define Hc 128
#define Bc 256
#define MBLK 4
#define NBLOCKS 64

typedef _Float16 half8 __attribute__((ext_vector_type(8)));
typedef float f32x4 __attribute__((ext_vector_type(4)));

#define MFMA_F16(A, B, C) __builtin_amdgcn_mfma_f32_16x16x32_f16((A), (B), (C), 0, 0, 0)

__device__ __forceinline__ float fast_sigmoid(float x) {
    return __builtin_amdgcn_rcpf(1.0f + __expf(-x));
}
__device__ __forceinline__ float fast_tanh(float x) {
    return 1.0f - 2.0f * __builtin_amdgcn_rcpf(__expf(2.0f * x) + 1.0f);
}

__global__ __launch_bounds__(512, 2) void gru_mfma_kernel(
    const float* __restrict__ input,   // [B][T][I]
    const float* __restrict__ W_ih,    // [3H][I]
    const float* __restrict__ W_hh,    // [3H][H]
    const float* __restrict__ b_ih,    // [3H]
    const float* __restrict__ b_hh,    // [3H]
    float* __restrict__ out)           // states [B][T][H] then hT [B][H]
{
    const int blk = blockIdx.x;
    const int tid = threadIdx.x;
    const int l   = tid & 63;
    const int w   = tid >> 6;    // wave 0..7
    const int ln  = l & 15;      // A-row m / B-col n offset
    const int lg  = l >> 4;      // k-group 0..3
    const int j   = w * 16 + ln; // this lane's gate column / h-unit

    __shared__ __align__(16) _Float16 hbuf[2][16][136];  // pad tile-rows stay 0
    __shared__ __align__(16) _Float16 xbuf[2][16][72];   // row 4b'+i = x(t0+i) of batch b'

    // ---------- persistent B-fragments (identical to r11..r21, verified) ------
    half8 bh[3][4], bx[3][2];
#pragma unroll
    for (int g = 0; g < 3; ++g) {
        const float* rw = W_hh + (size_t)(g * Hc + j) * Hc;
#pragma unroll
        for (int kc = 0; kc < 4; ++kc) {
            const float* p = rw + kc * 32 + lg * 8;
            half8 f;
#pragma unroll
            for (int e = 0; e < 8; ++e) f[e] = (_Float16)p[e];
            bh[g][kc] = f;
        }
        const float* rx = W_ih + (size_t)(g * Hc + j) * Ic;
#pragma unroll
        for (int kc = 0; kc < 2; ++kc) {
            const float* p = rx + kc * 32 + lg * 8;
            half8 f;
#pragma unroll
            for (int e = 0; e < 8; ++e) f[e] = (_Float16)p[e];
            bx[g][kc] = f;
        }
    }

    const float br0 = b_ih[j] + b_hh[j];
    const float bz0 = b_ih[Hc + j] + b_hh[Hc + j];
    const float bnx = b_ih[2 * Hc + j];
    const float bnh = b_hh[2 * Hc + j];

    // ---------- staging: 16 stagers = (batch b' = sm>>2) x (offset i = sm&3) --
    const int sm   = tid >> 5;          // 0..15 == xbuf tile row
    const int sk   = (tid & 31) * 2;
    const int ioff = sm & 3;
    const float* inrow = input + (size_t)(blk * MBLK + (sm >> 2)) * Tc * Ic + sk;

    // zero hbuf (h(-1)=0; pad tile-rows stay 0). xbuf fully staged before reads.
    for (int i = tid; i < 2 * 16 * 136; i += 512) (&hbuf[0][0][0])[i] = (_Float16)0.0f;

    {   // stage window 0: xbuf[0][sm] = x(ioff) of batch sm>>2
        float2 v0 = *reinterpret_cast<const float2*>(inrow + (size_t)ioff * Ic);
        union { _Float16 h[2]; unsigned u; } p0;
        p0.h[0] = (_Float16)v0.x; p0.h[1] = (_Float16)v0.y;
        *reinterpret_cast<unsigned*>(&xbuf[0][sm][sk]) = p0.u;
    }
    // prefetch regs for window 1: x(4+ioff)
    float2 xpre = *reinterpret_cast<const float2*>(inrow + (size_t)(4 + ioff) * Ic);
    __syncthreads();

    f32x4 cxr, cxz, cxn;   // window x-proj (+bias), elem i consumed at step t0+i
    float hold = 0.f;

    const int bA = blk * MBLK + lg;   // this lane's batch row
    const int tA = 4 * lg;            // its h tile row
    float* sP  = out + (size_t)bA * Tc * Hc + j;
    float* hTp = out + (size_t)Bc * Tc * Hc + (size_t)bA * Hc + j;

// window-start step: h-dot + x-block + staging (PAR=0)
#define GRU_STEP_X(T0_)                                                         \
    {                                                                           \
        __syncthreads();                                                        \
        const _Float16* hrp = &hbuf[1][ln][lg * 8];                             \
        half8 ha0 = *reinterpret_cast<const half8*>(hrp);                       \
        half8 ha1 = *reinterpret_cast<const half8*>(hrp + 32);                  \
        half8 ha2 = *reinterpret_cast<const half8*>(hrp + 64);                  \
        half8 ha3 = *reinterpret_cast<const half8*>(hrp + 96);                  \
        f32x4 hr = {0.f, 0.f, 0.f, 0.f};                                        \
        f32x4 hz = {0.f, 0.f, 0.f, 0.f};                                        \
        f32x4 hn = {bnh, bnh, bnh, bnh};                                        \
        hr = MFMA_F16(ha0, bh[0][0], hr); hz = MFMA_F16(ha0, bh[1][0], hz);     \
        hn = MFMA_F16(ha0, bh[2][0], hn);                                       \
        hr = MFMA_F16(ha1, bh[0][1], hr); hz = MFMA_F16(ha1, bh[1][1], hz);     \
        hn = MFMA_F16(ha1, bh[2][1], hn);                                       \
        hr = MFMA_F16(ha2, bh[0][2], hr); hz = MFMA_F16(ha2, bh[1][2], hz);     \
        hn = MFMA_F16(ha2, bh[2][2], hn);                                       \
        hr = MFMA_F16(ha3, bh[0][3], hr); hz = MFMA_F16(ha3, bh[1][3], hz);     \
        hn = MFMA_F16(ha3, bh[2][3], hn);                                       \
        /* x-block for steps T0_..T0_+3 */                                      \
        const int p4 = ((T0_) >> 2) & 1;                                        \
        const _Float16* xrp = &xbuf[p4][ln][lg * 8];                            \
        half8 xa0 = *reinterpret_cast<const half8*>(xrp);                       \
        half8 xa1 = *reinterpret_cast<const half8*>(xrp + 32);                  \
        cxr = (f32x4){br0, br0, br0, br0};                                      \
        cxz = (f32x4){bz0, bz0, bz0, bz0};                                      \
        cxn = (f32x4){bnx, bnx, bnx, bnx};                                      \
        cxr = MFMA_F16(xa0, bx[0][0], cxr); cxr = MFMA_F16(xa1, bx[0][1], cxr); \
        cxz = MFMA_F16(xa0, bx[1][0], cxz); cxz = MFMA_F16(xa1, bx[1][1], cxz); \
        cxn = MFMA_F16(xa0, bx[2][0], cxn); cxn = MFMA_F16(xa1, bx[2][1], cxn); \
        /* stage next window's rows from regs; load regs for window T0_+8 */    \
        {                                                                       \
            union { _Float16 h[2]; unsigned u; } pk;                            \
            pk.h[0] = (_Float16)xpre.x; pk.h[1] = (_Float16)xpre.y;             \
            *reinterpret_cast<unsigned*>(&xbuf[p4 ^ 1][sm][sk]) = pk.u;         \
            int rT = (T0_) + 8 + ioff; if (rT > Tc - 1) rT = Tc - 1;            \
            xpre = *reinterpret_cast<const float2*>(inrow + (size_t)rT * Ic);   \
        }                                                                       \
        const float rg = fast_sigmoid(hr[0] + cxr[0]);                          \
        const float zg = fast_sigmoid(hz[0] + cxz[0]);                          \
        const float nv = fast_tanh(cxn[0] + rg * hn[0]);                        \
        const float hN = nv + zg * (hold - nv);                                 \
        hbuf[0][tA][j] = (_Float16)hN;                                          \
        *sP = hN; sP += Hc;                                                     \
        hold = hN;                                                              \
    }

// plain step: h-dot only; consumes window elem I_ (PAR = I_&1)
#define GRU_STEP_N(T_, I_)                                                      \
    {                                                                           \
        __syncthreads();                                                        \
        const _Float16* hrp = &hbuf[1 - ((I_) & 1)][ln][lg * 8];                \
        half8 ha0 = *reinterpret_cast<const half8*>(hrp);                       \
        half8 ha1 = *reinterpret_cast<const half8*>(hrp + 32);                  \
        half8 ha2 = *reinterpret_cast<const half8*>(hrp + 64);                  \
        half8 ha3 = *reinterpret_cast<const half8*>(hrp + 96);                  \
        f32x4 hr = {0.f, 0.f, 0.f, 0.f};                                        \
        f32x4 hz = {0.f, 0.f, 0.f, 0.f};                                        \
        f32x4 hn = {bnh, bnh, bnh, bnh};                                        \
        hr = MFMA_F16(ha0, bh[0][0], hr); hz = MFMA_F16(ha0, bh[1][0], hz);     \
        hn = MFMA_F16(ha0, bh[2][0], hn);                                       \
        hr = MFMA_F16(ha1, bh[0][1], hr); hz = MFMA_F16(ha1, bh[1][1], hz);     \
        hn = MFMA_F16(ha1, bh[2][1], hn);                                       \
        hr = MFMA_F16(ha2, bh[0][2], hr); hz = MFMA_F16(ha2, bh[1][2], hz);     \
        hn = MFMA_F16(ha2, bh[2][2], hn);                                       \
        hr = MFMA_F16(ha3, bh[0][3], hr); hz = MFMA_F16(ha3, bh[1][3], hz);     \
        hn = MFMA_F16(ha3, bh[2][3], hn);                                       \
        const float rg = fast_sigmoid(hr[0] + cxr[I_]);                         \
        const float zg = fast_sigmoid(hz[0] + cxz[I_]);                         \
        const float nv = fast_tanh(cxn[I_] + rg * hn[0]);                       \
        const float hN = nv + zg * (hold - nv);                                 \
        hbuf[(I_) & 1][tA][j] = (_Float16)hN;                                   \
        *sP = hN; sP += Hc;                                                     \
        if ((T_) == Tc - 1) *hTp = hN;                                          \
        hold = hN;                                                              \
    }

    for (int t0 = 0; t0 < Tc; t0 += 4) {
        GRU_STEP_X(t0);
        GRU_STEP_N(t0 + 1, 1);
        GRU_STEP_N(t0 + 2, 2);
        GRU_STEP_N(t0 + 3, 3);
    }
#undef GRU_STEP_X
#undef GRU_STEP_N
}

extern "C" void kernel_launch(void* const* d_in, const int* in_sizes, int n_in,
                              void* d_out, int out_size, void* d_ws, size_t ws_size,
                              hipStream_t stream) {
    const float* input = (const float*)d_in[0];
    const float* W_ih  = (const float*)d_in[1];
    const float* W_hh  = (const float*)d_in[2];
    const float* b_ih  = (const float*)d_in[3];
    const float* b_hh  = (const float*)d_in[4];
    float* out = (float*)d_out;
    (void)in_sizes; (void)n_in; (void)d_ws; (void)ws_size; (void)out_size;

    gru_mfma_kernel<<<NBLOCKS, 512, 0, stream>>>(input, W_ih, W_hh, b_ih, b_hh, out);
}

// Round 24
// 353.454 us; speedup vs baseline: 1.7086x; 1.0055x over previous
//
#include <hip/hip_runtime.h>

// GRU: B=256, T=1000, I=64, H=128 (3H=384).
// Round-24 = r23 pipelining with the step_2 offset bug fixed.
// r23 failed (absmax 1.73) from precedence: `cast<half8*>(&xbuf[..][lg*8] + 4)`
// = element lg*8+4 (the +4 bound to _Float16*), not the second k-chunk at
// lg*8+32. Fixed by direct element index. Pipelining logic unchanged:
// next window's x-proj built during current window's steps 1,2 (3 indep
// MFMAs each); step_X swaps cx<-nx. MFMA load 18/12/12/12 -> 12/15/15/12.

#define Tc 1000
#define Ic 64
#define Hc 128
#define Bc 256
#define MBLK 4
#define NBLOCKS 64

typedef _Float16 half8 __attribute__((ext_vector_type(8)));
typedef float f32x4 __attribute__((ext_vector_type(4)));

#define MFMA_F16(A, B, C) __builtin_amdgcn_mfma_f32_16x16x32_f16((A), (B), (C), 0, 0, 0)

__device__ __forceinline__ float fast_sigmoid(float x) {
    return __builtin_amdgcn_rcpf(1.0f + __expf(-x));
}
__device__ __forceinline__ float fast_tanh(float x) {
    return 1.0f - 2.0f * __builtin_amdgcn_rcpf(__expf(2.0f * x) + 1.0f);
}

__global__ __launch_bounds__(512, 2) void gru_mfma_kernel(
    const float* __restrict__ input,   // [B][T][I]
    const float* __restrict__ W_ih,    // [3H][I]
    const float* __restrict__ W_hh,    // [3H][H]
    const float* __restrict__ b_ih,    // [3H]
    const float* __restrict__ b_hh,    // [3H]
    float* __restrict__ out)           // states [B][T][H] then hT [B][H]
{
    const int blk = blockIdx.x;
    const int tid = threadIdx.x;
    const int l   = tid & 63;
    const int w   = tid >> 6;    // wave 0..7
    const int ln  = l & 15;      // A-row m / B-col n offset
    const int lg  = l >> 4;      // k-group 0..3
    const int j   = w * 16 + ln; // this lane's gate column / h-unit

    __shared__ __align__(16) _Float16 hbuf[2][16][136];  // pad tile-rows stay 0
    __shared__ __align__(16) _Float16 xbuf[2][16][72];   // row 4b'+i = x(t0+i) of batch b'

    // ---------- persistent B-fragments (identical to r11..r22, verified) ------
    half8 bh[3][4], bx[3][2];
#pragma unroll
    for (int g = 0; g < 3; ++g) {
        const float* rw = W_hh + (size_t)(g * Hc + j) * Hc;
#pragma unroll
        for (int kc = 0; kc < 4; ++kc) {
            const float* p = rw + kc * 32 + lg * 8;
            half8 f;
#pragma unroll
            for (int e = 0; e < 8; ++e) f[e] = (_Float16)p[e];
            bh[g][kc] = f;
        }
        const float* rx = W_ih + (size_t)(g * Hc + j) * Ic;
#pragma unroll
        for (int kc = 0; kc < 2; ++kc) {
            const float* p = rx + kc * 32 + lg * 8;
            half8 f;
#pragma unroll
            for (int e = 0; e < 8; ++e) f[e] = (_Float16)p[e];
            bx[g][kc] = f;
        }
    }

    const float br0 = b_ih[j] + b_hh[j];
    const float bz0 = b_ih[Hc + j] + b_hh[Hc + j];
    const float bnx = b_ih[2 * Hc + j];
    const float bnh = b_hh[2 * Hc + j];

    // ---------- staging: 16 stagers = (batch b' = sm>>2) x (offset i = sm&3) --
    const int sm   = tid >> 5;          // 0..15 == xbuf tile row
    const int sk   = (tid & 31) * 2;
    const int ioff = sm & 3;
    const float* inrow = input + (size_t)(blk * MBLK + (sm >> 2)) * Tc * Ic + sk;

    // zero hbuf (h(-1)=0; pad tile-rows stay 0). xbuf fully staged before reads.
    for (int i = tid; i < 2 * 16 * 136; i += 512) (&hbuf[0][0][0])[i] = (_Float16)0.0f;

    {   // stage window 0: xbuf[0][sm] = x(ioff) of batch sm>>2
        float2 v0 = *reinterpret_cast<const float2*>(inrow + (size_t)ioff * Ic);
        union { _Float16 h[2]; unsigned u; } p0;
        p0.h[0] = (_Float16)v0.x; p0.h[1] = (_Float16)v0.y;
        *reinterpret_cast<unsigned*>(&xbuf[0][sm][sk]) = p0.u;
    }
    // prefetch regs for window 1: x(4+ioff)
    float2 xpre = *reinterpret_cast<const float2*>(inrow + (size_t)(4 + ioff) * Ic);
    __syncthreads();

    // prologue: window-0 x-proj into nx (step_X(0) will swap it into cx)
    f32x4 nxr, nxz, nxn;
    {
        const _Float16* xrp = &xbuf[0][ln][lg * 8];
        half8 xa0 = *reinterpret_cast<const half8*>(xrp);
        half8 xa1 = *reinterpret_cast<const half8*>(xrp + 32);
        nxr = (f32x4){br0, br0, br0, br0};
        nxz = (f32x4){bz0, bz0, bz0, bz0};
        nxn = (f32x4){bnx, bnx, bnx, bnx};
        nxr = MFMA_F16(xa0, bx[0][0], nxr); nxr = MFMA_F16(xa1, bx[0][1], nxr);
        nxz = MFMA_F16(xa0, bx[1][0], nxz); nxz = MFMA_F16(xa1, bx[1][1], nxz);
        nxn = MFMA_F16(xa0, bx[2][0], nxn); nxn = MFMA_F16(xa1, bx[2][1], nxn);
    }
    f32x4 cxr, cxz, cxn;   // current window x-proj (+bias); elem i used at t0+i
    float hold = 0.f;

    const int bA = blk * MBLK + lg;   // this lane's batch row
    const int tA = 4 * lg;            // its h tile row
    float* sP  = out + (size_t)bA * Tc * Hc + j;
    float* hTp = out + (size_t)Bc * Tc * Hc + (size_t)bA * Hc + j;

// h-dot macro body (shared): reads hbuf[RP_], produces hr/hz/hn
#define HDOT(RP_)                                                               \
        const _Float16* hrp = &hbuf[RP_][ln][lg * 8];                           \
        half8 ha0 = *reinterpret_cast<const half8*>(hrp);                       \
        half8 ha1 = *reinterpret_cast<const half8*>(hrp + 32);                  \
        half8 ha2 = *reinterpret_cast<const half8*>(hrp + 64);                  \
        half8 ha3 = *reinterpret_cast<const half8*>(hrp + 96);                  \
        f32x4 hr = {0.f, 0.f, 0.f, 0.f};                                        \
        f32x4 hz = {0.f, 0.f, 0.f, 0.f};                                        \
        f32x4 hn = {bnh, bnh, bnh, bnh};                                        \
        hr = MFMA_F16(ha0, bh[0][0], hr); hz = MFMA_F16(ha0, bh[1][0], hz);     \
        hn = MFMA_F16(ha0, bh[2][0], hn);                                       \
        hr = MFMA_F16(ha1, bh[0][1], hr); hz = MFMA_F16(ha1, bh[1][1], hz);     \
        hn = MFMA_F16(ha1, bh[2][1], hn);                                       \
        hr = MFMA_F16(ha2, bh[0][2], hr); hz = MFMA_F16(ha2, bh[1][2], hz);     \
        hn = MFMA_F16(ha2, bh[2][2], hn);                                       \
        hr = MFMA_F16(ha3, bh[0][3], hr); hz = MFMA_F16(ha3, bh[1][3], hz);     \
        hn = MFMA_F16(ha3, bh[2][3], hn);

#define GATE(I_, WPAR_, T_)                                                     \
        const float rg = fast_sigmoid(hr[0] + cxr[I_]);                         \
        const float zg = fast_sigmoid(hz[0] + cxz[I_]);                         \
        const float nv = fast_tanh(cxn[I_] + rg * hn[0]);                       \
        const float hN = nv + zg * (hold - nv);                                 \
        hbuf[WPAR_][tA][j] = (_Float16)hN;                                      \
        *sP = hN; sP += Hc;                                                     \
        if ((T_) == Tc - 1) *hTp = hN;                                          \
        hold = hN;

// window-start step: swap in prebuilt x-proj; h-dot; stage next window's x
#define GRU_STEP_X(T0_)                                                         \
    {                                                                           \
        __syncthreads();                                                        \
        cxr = nxr; cxz = nxz; cxn = nxn;                                        \
        HDOT(1)                                                                 \
        const int p4 = ((T0_) >> 2) & 1;                                        \
        {                                                                       \
            union { _Float16 h[2]; unsigned u; } pk;                            \
            pk.h[0] = (_Float16)xpre.x; pk.h[1] = (_Float16)xpre.y;             \
            *reinterpret_cast<unsigned*>(&xbuf[p4 ^ 1][sm][sk]) = pk.u;         \
            int rT = (T0_) + 8 + ioff; if (rT > Tc - 1) rT = Tc - 1;            \
            xpre = *reinterpret_cast<const float2*>(inrow + (size_t)rT * Ic);   \
        }                                                                       \
        GATE(0, 0, T0_)                                                         \
    }

// plain step 1: h-dot + first half of next window's x-proj (3 indep MFMAs)
#define GRU_STEP_1(T_, P4_)                                                     \
    {                                                                           \
        __syncthreads();                                                        \
        HDOT(0)                                                                 \
        half8 xa0 = *reinterpret_cast<const half8*>(&xbuf[(P4_) ^ 1][ln][lg * 8]); \
        nxr = (f32x4){br0, br0, br0, br0};                                      \
        nxz = (f32x4){bz0, bz0, bz0, bz0};                                      \
        nxn = (f32x4){bnx, bnx, bnx, bnx};                                      \
        nxr = MFMA_F16(xa0, bx[0][0], nxr);                                     \
        nxz = MFMA_F16(xa0, bx[1][0], nxz);                                     \
        nxn = MFMA_F16(xa0, bx[2][0], nxn);                                     \
        GATE(1, 1, T_)                                                          \
    }

// plain step 2: h-dot + second half of next window's x-proj
// (FIXED: element index lg*8+32, not half8-ptr precedence bug)
#define GRU_STEP_2(T_, P4_)                                                     \
    {                                                                           \
        __syncthreads();                                                        \
        HDOT(1)                                                                 \
        half8 xa1 = *reinterpret_cast<const half8*>(&xbuf[(P4_) ^ 1][ln][lg * 8 + 32]); \
        nxr = MFMA_F16(xa1, bx[0][1], nxr);                                     \
        nxz = MFMA_F16(xa1, bx[1][1], nxz);                                     \
        nxn = MFMA_F16(xa1, bx[2][1], nxn);                                     \
        GATE(2, 0, T_)                                                          \
    }

// plain step 3: h-dot only
#define GRU_STEP_3(T_)                                                          \
    {                                                                           \
        __syncthreads();                                                        \
        HDOT(0)                                                                 \
        GATE(3, 1, T_)                                                          \
    }

    for (int t0 = 0; t0 < Tc; t0 += 4) {
        const int p4 = (t0 >> 2) & 1;
        GRU_STEP_X(t0);
        GRU_STEP_1(t0 + 1, p4);
        GRU_STEP_2(t0 + 2, p4);
        GRU_STEP_3(t0 + 3);
    }
#undef GRU_STEP_X
#undef GRU_STEP_1
#undef GRU_STEP_2
#undef GRU_STEP_3
#undef HDOT
#undef GATE
}

extern "C" void kernel_launch(void* const* d_in, const int* in_sizes, int n_in,
                              void* d_out, int out_size, void* d_ws, size_t ws_size,
                              hipStream_t stream) {
    const float* input = (const float*)d_in[0];
    const float* W_ih  = (const float*)d_in[1];
    const float* W_hh  = (const float*)d_in[2];
    const float* b_ih  = (const float*)d_in[3];
    const float* b_hh  = (const float*)d_in[4];
    float* out = (float*)d_out;
    (void)in_sizes; (void)n_in; (void)d_ws; (void)ws_size; (void)out_size;

    gru_mfma_kernel<<<NBLOCKS, 512, 0, stream>>>(input, W_ih, W_hh, b_ih, b_hh, out);
}